// Round 15
// baseline (837.650 us; speedup 1.0000x reference)
//
#include <hip/hip_runtime.h>
#include <math.h>

#define N_NODES 100000
#define N_EDGES 1600000
#define SCAN_BS 1024
#define NBK 8              // src buckets (src>>14): 16384 nodes = 2MB of m @C=64
#define BKSH 14
#define NBINS (N_NODES*NBK)
#define NPART 196          // dst partitions (dst>>9): 512 dsts, ~64KB esrc window
#define PCAP 1536          // per (xcd,part) capacity; mean 1020, sigma 32

typedef __attribute__((ext_vector_type(8))) short bf8_t;   // 8 bf16 in 4 VGPRs
typedef __attribute__((ext_vector_type(4))) float f4_t;
typedef unsigned short us;
typedef unsigned long long ull;

__device__ __forceinline__ float sigmoidf_(float x){ return 1.f/(1.f + expf(-x)); }
__device__ __forceinline__ float eluf_(float x){ return x > 0.f ? x : expm1f(x); }
__device__ __forceinline__ us f2bf(float x){
  unsigned u = __float_as_uint(x);
  unsigned r = u + 0x7FFFu + ((u>>16)&1u);
  return (us)(r>>16);
}
__device__ __forceinline__ float bf2f(us v){
  return __uint_as_float(((unsigned)v)<<16);
}

// ---------------- fused weight prep (one kernel, segment-dispatched) ----------
__global__ void prep_all(const float* __restrict__ Wih1, const float* __restrict__ Whh1,
                         const float* __restrict__ Wih2, const float* __restrict__ Whh2,
                         const float* __restrict__ W1,   const float* __restrict__ W2,
                         const float* __restrict__ fc1w, const float* __restrict__ fc2w,
                         const float* __restrict__ fc2b,
                         us* Wihb1, us* Whhb1, us* Wihb2, us* Whhb2,
                         us* Wtb1, us* Wtb2, us* fc1wb, us* fc2wpb, float* fc2bp){
  int i = blockIdx.x*256 + threadIdx.x;
  if (i < 3072) { Wihb1[i]=f2bf(Wih1[i]); return; } i -= 3072;
  if (i < 3072) { Whhb1[i]=f2bf(Whh1[i]); return; } i -= 3072;
  if (i < 12288){ Wihb2[i]=f2bf(Wih2[i]); return; } i -= 12288;
  if (i < 12288){ Whhb2[i]=f2bf(Whh2[i]); return; } i -= 12288;
  if (i < 3072) { int k=i%32, c=(i/32)%32, m=i/1024;           // Wt[m][c][k] = W[m][k][c]
                  Wtb1[i]=f2bf(W1[m*1024 + k*32 + c]); return; } i -= 3072;
  if (i < 12288){ int k=i%64, c=(i/64)%64, m=i/4096;
                  Wtb2[i]=f2bf(W2[m*4096 + k*64 + c]); return; } i -= 12288;
  if (i < 8192) { fc1wb[i]=f2bf(fc1w[i]); return; } i -= 8192;
  if (i < 2048) { int c=i/128, k=i%128;
                  fc2wpb[i]=(c<10)?f2bf(fc2w[c*128+k]):(us)0; return; } i -= 2048;
  if (i < 16)   { fc2bp[i] = (i<10)? fc2b[i] : 0.f; }
}

// ---------------- bucketed CSR build: key = dst*NBK + (src>>BKSH) ----------
__global__ void zero_counts(int* cnt, int* cur, int n, int* pcur, int np){
  int i = blockIdx.x*blockDim.x + threadIdx.x;
  if (i < n){ cnt[i]=0; cur[i]=0; }
  if (i < np) pcur[i]=0;
}
// pass 1: count bins + partition edges into 8x196 XCD-local append buffers.
// pack: src(17) | dst(17)<<17 | ew-bf16(16)<<34. Regular stores (lines must
// linger in L2 to accumulate 8 packs each -> full-line writeback).
__global__ void part_kernel(const int* __restrict__ ei, const float* __restrict__ ea,
    int* __restrict__ cnt, int* __restrict__ pcur, ull* __restrict__ pbuf, int e){
  int i0 = (blockIdx.x*blockDim.x + threadIdx.x)*2;
  int xcd = blockIdx.x & 7;
  #pragma unroll
  for (int j=0;j<2;j++){
    int i = i0 + j;
    if (i < e){
      int s = ei[i], d = ei[N_EDGES + i];
      atomicAdd(&cnt[d*NBK + (s>>BKSH)], 1);
      unsigned ew16 = f2bf(ea[i]);
      int slot = xcd*NPART + (d>>9);
      int pos = atomicAdd(&pcur[slot], 1);
      pbuf[(size_t)slot*PCAP + pos] =
          (ull)(unsigned)s | ((ull)(unsigned)d << 17) | ((ull)ew16 << 34);
    }
  }
}
__global__ void scan1_kernel(const int* __restrict__ cnt, int* __restrict__ pre,
                             int* __restrict__ bsum, int n){
  __shared__ int sh[SCAN_BS];
  int t = threadIdx.x, gi = blockIdx.x*SCAN_BS + t;
  int v = (gi < n) ? cnt[gi] : 0;
  sh[t] = v;
  __syncthreads();
  for (int off=1; off<SCAN_BS; off<<=1){
    int u = (t>=off)?sh[t-off]:0;
    __syncthreads();
    sh[t] += u;
    __syncthreads();
  }
  if (gi < n) pre[gi] = sh[t] - v;
  if (t == SCAN_BS-1) bsum[blockIdx.x] = sh[t];
}
__global__ void scan2_kernel(int* __restrict__ bsum, int nb){
  __shared__ int sh[1024];
  int t = threadIdx.x;
  int v = (t < nb) ? bsum[t] : 0;
  sh[t] = v;
  __syncthreads();
  for (int off=1; off<1024; off<<=1){
    int u = (t>=off)?sh[t-off]:0;
    __syncthreads();
    sh[t] += u;
    __syncthreads();
  }
  if (t < nb) bsum[t] = sh[t] - v;
}
__global__ void scan3_kernel(const int* __restrict__ pre, const int* __restrict__ bsum,
                             int* __restrict__ rs2, int total){
  int i = blockIdx.x*blockDim.x + threadIdx.x;
  if (i < total) rs2[i] = pre[i] + bsum[i/SCAN_BS];
  if (i == 0) rs2[total] = N_EDGES;
}
// pass 2: per partition (2 blocks each: xcd 0-3 / 4-7), scatter into the
// partition's CONTIGUOUS ~64KB esrc window -> full-line L2 writebacks.
__global__ void scatter2_kernel(const ull* __restrict__ pbuf, const int* __restrict__ pcur,
    const int* __restrict__ rs2, int* __restrict__ cur, ull* __restrict__ esrc){
  int p = blockIdx.x >> 1;
  int xlo = (blockIdx.x & 1)*4;
  for (int x=xlo; x<xlo+4; x++){
    int slot = x*NPART + p;
    int len = pcur[slot];
    const ull* seg = pbuf + (size_t)slot*PCAP;
    for (int i=threadIdx.x; i<len; i+=256){
      ull v = seg[i];
      int src = (int)(v & 0x1FFFFu);
      int dst = (int)((v>>17) & 0x1FFFFu);
      unsigned ew16 = (unsigned)((v>>34) & 0xFFFFu);
      int bin = dst*NBK + (src>>BKSH);
      int pos = rs2[bin] + atomicAdd(&cur[bin], 1);
      esrc[pos] = (ull)(unsigned)src | ((ull)(ew16<<16) << 32);
    }
  }
}

// ---------------- elementwise ----------------
__global__ void pad_x_kernel(const float* __restrict__ x, float* __restrict__ h,
                             us* __restrict__ hb, int n){
  int i = blockIdx.x*blockDim.x + threadIdx.x;
  if (i < n*32){
    int node = i >> 5, c = i & 31;
    float v = (c < 16) ? x[node*16 + c] : 0.f;
    h[i] = v;
    hb[i] = f2bf(v);
  }
}
__global__ void transition_kernel(const float* __restrict__ h1, float* __restrict__ h2,
                                  us* __restrict__ h2b, int n){
  int i = blockIdx.x*blockDim.x + threadIdx.x;
  if (i < n*64){
    int node = i >> 6, c = i & 63;
    float v = (c < 32) ? eluf_(h1[node*32 + c]) : 0.f;
    h2[i] = v;
    h2b[i] = f2bf(v);
  }
}

// ---------------- m = h @ W via MFMA (layer-start only) ----------------
template<int C>
__global__ __launch_bounds__(256) void mgemm_mfma(const us* __restrict__ hb,
    const us* __restrict__ Wtb, us* __restrict__ mb, int n){
  constexpr int NT = C/16, KS = C/32;
  int l = threadIdx.x & 63, w = threadIdx.x >> 6;
  int mbase = blockIdx.x*64 + w*16;
  if (mbase >= n) return;
  int lr = l & 15, lk = (l >> 4)*8;
  f4_t acc[NT];
  #pragma unroll
  for (int t=0;t<NT;t++) acc[t] = f4_t{0.f,0.f,0.f,0.f};
  #pragma unroll
  for (int ks=0; ks<KS; ks++){
    int k0 = ks*32 + lk;
    bf8_t a = *(const bf8_t*)(hb + (size_t)(mbase+lr)*C + k0);
    #pragma unroll
    for (int t=0;t<NT;t++){
      bf8_t b = *(const bf8_t*)(Wtb + (size_t)(t*16+lr)*C + k0);
      acc[t] = __builtin_amdgcn_mfma_f32_16x16x32_bf16(a, b, acc[t], 0, 0, 0);
    }
  }
  int dr = (l>>4)*4;
  #pragma unroll
  for (int t=0;t<NT;t++){
    #pragma unroll
    for (int r=0;r<4;r++){
      int node = mbase + dr + r;
      if (node < n)
        mb[(size_t)node*C + t*16 + lr] = f2bf(acc[t][r]);
    }
  }
}

// ---------------- agg: 8 channels/lane via uint4 gathers, 4-deep pipeline ----
template<int C>
__global__ void agg_kernel(const us* __restrict__ mb, const int* __restrict__ rs2,
    const ull* __restrict__ esrc, us* __restrict__ aggb, int n_nodes){
  constexpr int GPN = C/8;
  int gid = blockIdx.x*blockDim.x + threadIdx.x;
  int nn = gid / GPN, g8 = gid % GPN;
  if (nn >= n_nodes) return;
  int s = rs2[nn*NBK], e = rs2[nn*NBK + NBK];
  float acc[8];
  #pragma unroll
  for (int j=0;j<8;j++) acc[j] = -__builtin_inff();
  const us* mbg = mb + g8*8;
  int i = s;
  for (; i+4<=e; i+=4){
    ull e0 = esrc[i], e1 = esrc[i+1], e2 = esrc[i+2], e3 = esrc[i+3];
    uint4 v0 = *(const uint4*)(mbg + (size_t)(unsigned)(e0 & 0xFFFFFFFF)*C);
    uint4 v1 = *(const uint4*)(mbg + (size_t)(unsigned)(e1 & 0xFFFFFFFF)*C);
    uint4 v2 = *(const uint4*)(mbg + (size_t)(unsigned)(e2 & 0xFFFFFFFF)*C);
    uint4 v3 = *(const uint4*)(mbg + (size_t)(unsigned)(e3 & 0xFFFFFFFF)*C);
    float w0 = __int_as_float((int)(e0>>32)), w1 = __int_as_float((int)(e1>>32));
    float w2 = __int_as_float((int)(e2>>32)), w3 = __int_as_float((int)(e3>>32));
    unsigned a0[4] = {v0.x, v0.y, v0.z, v0.w};
    unsigned a1[4] = {v1.x, v1.y, v1.z, v1.w};
    unsigned a2[4] = {v2.x, v2.y, v2.z, v2.w};
    unsigned a3[4] = {v3.x, v3.y, v3.z, v3.w};
    #pragma unroll
    for (int q=0;q<4;q++){
      float x0 = fmaxf(__uint_as_float(a0[q]<<16)*w0, __uint_as_float(a1[q]<<16)*w1);
      float x1 = fmaxf(__uint_as_float(a2[q]<<16)*w2, __uint_as_float(a3[q]<<16)*w3);
      float y0 = fmaxf(__uint_as_float(a0[q]&0xFFFF0000u)*w0, __uint_as_float(a1[q]&0xFFFF0000u)*w1);
      float y1 = fmaxf(__uint_as_float(a2[q]&0xFFFF0000u)*w2, __uint_as_float(a3[q]&0xFFFF0000u)*w3);
      acc[2*q]   = fmaxf(acc[2*q],   fmaxf(x0, x1));
      acc[2*q+1] = fmaxf(acc[2*q+1], fmaxf(y0, y1));
    }
  }
  for (; i<e; i++){
    ull e0 = esrc[i];
    uint4 v0 = *(const uint4*)(mbg + (size_t)(unsigned)(e0 & 0xFFFFFFFF)*C);
    float w0 = __int_as_float((int)(e0>>32));
    unsigned a0[4] = {v0.x, v0.y, v0.z, v0.w};
    #pragma unroll
    for (int q=0;q<4;q++){
      acc[2*q]   = fmaxf(acc[2*q],   __uint_as_float(a0[q]<<16)*w0);
      acc[2*q+1] = fmaxf(acc[2*q+1], __uint_as_float(a0[q]&0xFFFF0000u)*w0);
    }
  }
  unsigned r[8];
  #pragma unroll
  for (int j=0;j<8;j++) r[j] = (e > s) ? (unsigned)f2bf(acc[j]) : 0u;
  uint4 o;
  o.x = r[0] | (r[1]<<16); o.y = r[2] | (r[3]<<16);
  o.z = r[4] | (r[5]<<16); o.w = r[6] | (r[7]<<16);
  *(uint4*)(aggb + (size_t)nn*C + g8*8) = o;
}

// ---------------- fused GRU via MFMA; optionally computes next-iter m ------
template<int C, bool COMPUTE_M>
__global__ __launch_bounds__(256) void gru_mfma(
    const us* __restrict__ aggb, const us* __restrict__ hbin,
    const float* __restrict__ hfin,
    const us* __restrict__ Wihb, const us* __restrict__ Whhb,
    const float* __restrict__ bih, const float* __restrict__ bhh,
    const us* __restrict__ Wtb_next,
    float* __restrict__ hfout, us* __restrict__ hbout, us* __restrict__ mbout, int n){
  constexpr int NT = 3*C/16;
  constexpr int KS = C/32;
  constexpr int CT = C/16;
  constexpr int TST = C + 8;                     // LDS tile stride (bf16)
  constexpr int TSZ = COMPUTE_M ? 16*TST : 1;
  __shared__ us tlds[4][TSZ];
  int l = threadIdx.x & 63, w = threadIdx.x >> 6;
  int mbase = blockIdx.x*64 + w*16;
  int lr = l & 15, lk = (l >> 4)*8;
  f4_t accI[NT], accH[NT];
  #pragma unroll
  for (int t=0;t<NT;t++){ accI[t]=f4_t{0.f,0.f,0.f,0.f}; accH[t]=f4_t{0.f,0.f,0.f,0.f}; }
  #pragma unroll
  for (int ks=0; ks<KS; ks++){
    int k0 = ks*32 + lk;
    bf8_t aI = *(const bf8_t*)(aggb + (size_t)(mbase+lr)*C + k0);
    bf8_t aH = *(const bf8_t*)(hbin + (size_t)(mbase+lr)*C + k0);
    #pragma unroll
    for (int t=0;t<NT;t++){
      bf8_t bI = *(const bf8_t*)(Wihb + (size_t)(t*16+lr)*C + k0);
      accI[t] = __builtin_amdgcn_mfma_f32_16x16x32_bf16(aI, bI, accI[t], 0, 0, 0);
      bf8_t bH = *(const bf8_t*)(Whhb + (size_t)(t*16+lr)*C + k0);
      accH[t] = __builtin_amdgcn_mfma_f32_16x16x32_bf16(aH, bH, accH[t], 0, 0, 0);
    }
  }
  int dr = (l>>4)*4;
  us* tile = tlds[w];
  #pragma unroll
  for (int ct=0; ct<CT; ct++){
    int c = ct*16 + lr;
    float bR = bih[c],     cR = bhh[c];
    float bZ = bih[c+C],   cZ = bhh[c+C];
    float bN = bih[c+2*C], cN = bhh[c+2*C];
    #pragma unroll
    for (int r=0;r<4;r++){
      int i = mbase + dr + r;
      float giR = accI[ct][r] + bR,      ghR = accH[ct][r] + cR;
      float giZ = accI[CT+ct][r] + bZ,   ghZ = accH[CT+ct][r] + cZ;
      float giN = accI[2*CT+ct][r] + bN, ghN = accH[2*CT+ct][r] + cN;
      float rr = sigmoidf_(giR + ghR);
      float z  = sigmoidf_(giZ + ghZ);
      float nn = tanhf(giN + rr*ghN);
      float h  = hfin[(size_t)i*C + c];       // tail rows read adjacent ws: safe
      float ho = (1.f - z)*nn + z*h;
      us hob = f2bf(ho);
      if constexpr (COMPUTE_M)
        tile[(dr+r)*TST + c] = hob;
      if (i < n){
        hfout[(size_t)i*C + c] = ho;
        hbout[(size_t)i*C + c] = hob;
      }
    }
  }
  if constexpr (COMPUTE_M){
    __syncthreads();
    f4_t macc[CT];
    #pragma unroll
    for (int t=0;t<CT;t++) macc[t] = f4_t{0.f,0.f,0.f,0.f};
    #pragma unroll
    for (int ks=0; ks<KS; ks++){
      int k0 = ks*32 + lk;
      bf8_t a = *(const bf8_t*)(tile + lr*TST + k0);
      #pragma unroll
      for (int t=0;t<CT;t++){
        bf8_t b = *(const bf8_t*)(Wtb_next + (size_t)(t*16+lr)*C + k0);
        macc[t] = __builtin_amdgcn_mfma_f32_16x16x32_bf16(a, b, macc[t], 0, 0, 0);
      }
    }
    #pragma unroll
    for (int t=0;t<CT;t++){
      #pragma unroll
      for (int r=0;r<4;r++){
        int node = mbase + dr + r;
        if (node < n)
          mbout[(size_t)node*C + t*16 + lr] = f2bf(macc[t][r]);
      }
    }
  }
}

// ---------------- head via MFMA: elu -> fc1 -> elu -> fc2 -> log_softmax ----
__global__ __launch_bounds__(256) void head_mfma(const float* __restrict__ h2,
    const us* __restrict__ fc1wb, const float* __restrict__ fc1b,
    const us* __restrict__ fc2wpb, const float* __restrict__ fc2bp,
    float* __restrict__ out, int n){
  __shared__ __align__(16) us lds[4][16*136];
  int l = threadIdx.x & 63, w = threadIdx.x >> 6;
  int mbase = blockIdx.x*64 + w*16;          // no early return: barrier stays uniform
  int lr = l & 15, lk = (l >> 4)*8;
  int dr = (l>>4)*4;
  // ---- fc1 ----
  f4_t acc1[8];
  #pragma unroll
  for (int t=0;t<8;t++) acc1[t] = f4_t{0.f,0.f,0.f,0.f};
  #pragma unroll
  for (int ks=0; ks<2; ks++){
    int k0 = ks*32 + lk;
    const float* hp = h2 + (size_t)(mbase+lr)*64 + k0;   // tail rows read scratch: safe
    float4 v0 = *(const float4*)hp;
    float4 v1 = *(const float4*)(hp+4);
    bf8_t a;
    a[0]=(short)f2bf(eluf_(v0.x)); a[1]=(short)f2bf(eluf_(v0.y));
    a[2]=(short)f2bf(eluf_(v0.z)); a[3]=(short)f2bf(eluf_(v0.w));
    a[4]=(short)f2bf(eluf_(v1.x)); a[5]=(short)f2bf(eluf_(v1.y));
    a[6]=(short)f2bf(eluf_(v1.z)); a[7]=(short)f2bf(eluf_(v1.w));
    #pragma unroll
    for (int t=0;t<8;t++){
      bf8_t b = *(const bf8_t*)(fc1wb + (size_t)(t*16+lr)*64 + k0);
      acc1[t] = __builtin_amdgcn_mfma_f32_16x16x32_bf16(a, b, acc1[t], 0, 0, 0);
    }
  }
  // ---- bias + elu, transpose through LDS ----
  us* tile = lds[w];
  #pragma unroll
  for (int t=0;t<8;t++){
    float b1 = fc1b[t*16 + lr];
    #pragma unroll
    for (int r=0;r<4;r++)
      tile[(dr+r)*136 + t*16 + lr] = f2bf(eluf_(acc1[t][r] + b1));
  }
  __syncthreads();
  // ---- fc2 ----
  f4_t acc2 = f4_t{0.f,0.f,0.f,0.f};
  #pragma unroll
  for (int ks=0; ks<4; ks++){
    int k0 = ks*32 + lk;
    bf8_t a = *(const bf8_t*)(tile + lr*136 + k0);
    bf8_t b = *(const bf8_t*)(fc2wpb + (size_t)lr*128 + k0);
    acc2 = __builtin_amdgcn_mfma_f32_16x16x32_bf16(a, b, acc2, 0, 0, 0);
  }
  // ---- log_softmax over classes (16 lanes = 16 cols, 10 valid) ----
  float b2 = fc2bp[lr];
  #pragma unroll
  for (int r=0;r<4;r++){
    float val = acc2[r] + b2;
    float vm = (lr < 10) ? val : -__builtin_inff();
    #pragma unroll
    for (int m=1;m<16;m<<=1) vm = fmaxf(vm, __shfl_xor(vm, m, 64));
    float ex = (lr < 10) ? expf(val - vm) : 0.f;
    #pragma unroll
    for (int m=1;m<16;m<<=1) ex += __shfl_xor(ex, m, 64);
    float lse = vm + logf(ex);
    int node = mbase + dr + r;
    if (lr < 10 && node < n) out[(size_t)node*10 + lr] = val - lse;
  }
}

extern "C" void kernel_launch(void* const* d_in, const int* in_sizes, int n_in,
                              void* d_out, int out_size, void* d_ws, size_t ws_size,
                              hipStream_t stream){
  const float* x    = (const float*)d_in[0];
  const int*   ei   = (const int*)  d_in[1];
  const float* ea   = (const float*)d_in[2];
  const float* W1   = (const float*)d_in[3];
  const float* Wih1 = (const float*)d_in[4];
  const float* Whh1 = (const float*)d_in[5];
  const float* bih1 = (const float*)d_in[6];
  const float* bhh1 = (const float*)d_in[7];
  const float* W2   = (const float*)d_in[8];
  const float* Wih2 = (const float*)d_in[9];
  const float* Whh2 = (const float*)d_in[10];
  const float* bih2 = (const float*)d_in[11];
  const float* bhh2 = (const float*)d_in[12];
  const float* fc1w = (const float*)d_in[13];
  const float* fc1b = (const float*)d_in[14];
  const float* fc2w = (const float*)d_in[15];
  const float* fc2b = (const float*)d_in[16];
  float* outp = (float*)d_out;

  char* ws = (char*)d_ws;
  size_t off = 0;
  auto alloc = [&](size_t bytes)->void*{
    void* p = ws + off;
    off += (bytes + 255) & ~size_t(255);
    return p;
  };
  float* hA   = (float*)alloc(sizeof(float)*N_NODES*32);
  float* hB   = (float*)alloc(sizeof(float)*N_NODES*64);
  us* hAb0    = (us*)alloc(sizeof(us)*N_NODES*32);
  us* hAb1    = (us*)alloc(sizeof(us)*N_NODES*32);
  us* hBb0    = (us*)alloc(sizeof(us)*N_NODES*64);
  us* hBb1    = (us*)alloc(sizeof(us)*N_NODES*64);
  us* mb      = (us*)alloc(sizeof(us)*N_NODES*64);
  us* aggb    = (us*)alloc(sizeof(us)*N_NODES*64);
  int* rs2    = (int*)alloc(sizeof(int)*(NBINS+1));
  int* cnt    = (int*)alloc(sizeof(int)*NBINS);
  int* cur    = (int*)alloc(sizeof(int)*NBINS);
  int* pre    = (int*)alloc(sizeof(int)*NBINS);
  int* bsum   = (int*)alloc(sizeof(int)*1024);
  ull* esrc   = (ull*)alloc(sizeof(ull)*N_EDGES);
  ull* pbuf   = (ull*)alloc(sizeof(ull)*8*NPART*PCAP);
  int* pcur   = (int*)alloc(sizeof(int)*8*NPART);
  us* Wihb1   = (us*)alloc(sizeof(us)*96*32);
  us* Whhb1   = (us*)alloc(sizeof(us)*96*32);
  us* Wihb2   = (us*)alloc(sizeof(us)*192*64);
  us* Whhb2   = (us*)alloc(sizeof(us)*192*64);
  us* Wtb1    = (us*)alloc(sizeof(us)*3*32*32);
  us* Wtb2    = (us*)alloc(sizeof(us)*3*64*64);
  us* fc1wb   = (us*)alloc(sizeof(us)*128*64);
  us* fc2wpb  = (us*)alloc(sizeof(us)*16*128);
  float* fc2bp= (float*)alloc(sizeof(float)*16);
  (void)ws_size; (void)in_sizes; (void)n_in; (void)out_size;

  const int n = N_NODES, e = N_EDGES;
  const int nbk = (NBINS + SCAN_BS - 1)/SCAN_BS;    // 782 <= 1024 (scan2 limit)
  const int gblk = (n + 63)/64;                      // 1563

  // fused weight prep: 56336 elements
  prep_all<<<(56336+255)/256,256,0,stream>>>(Wih1, Whh1, Wih2, Whh2, W1, W2,
      fc1w, fc2w, fc2b, Wihb1, Whhb1, Wihb2, Whhb2, Wtb1, Wtb2, fc1wb, fc2wpb, fc2bp);

  // bucketed CSR build (two-pass partition scatter)
  zero_counts<<<(NBINS+255)/256,256,0,stream>>>(cnt, cur, NBINS, pcur, 8*NPART);
  part_kernel<<<(e/2+255)/256,256,0,stream>>>(ei, ea, cnt, pcur, pbuf, e);
  scan1_kernel<<<nbk,SCAN_BS,0,stream>>>(cnt, pre, bsum, NBINS);
  scan2_kernel<<<1,1024,0,stream>>>(bsum, nbk);
  scan3_kernel<<<(NBINS+255)/256,256,0,stream>>>(pre, bsum, rs2, NBINS);
  scatter2_kernel<<<NPART*2,256,0,stream>>>(pbuf, pcur, rs2, cur, esrc);

  // layer 1 (C=32)
  pad_x_kernel<<<(n*32+255)/256,256,0,stream>>>(x, hA, hAb0, n);
  {
    us* c0 = hAb0; us* c1 = hAb1;
    mgemm_mfma<32><<<gblk,256,0,stream>>>(c0, Wtb1, mb, n);
    for (int i=0;i<3;i++){
      agg_kernel<32><<<((long long)n*4+255)/256,256,0,stream>>>(mb, rs2, esrc, aggb, n);
      if (i < 2)
        gru_mfma<32,true><<<gblk,256,0,stream>>>(aggb, c0, hA, Wihb1, Whhb1, bih1, bhh1,
                                                 Wtb1 + (i+1)*32*32, hA, c1, mb, n);
      else
        gru_mfma<32,false><<<gblk,256,0,stream>>>(aggb, c0, hA, Wihb1, Whhb1, bih1, bhh1,
                                                  nullptr, hA, c1, nullptr, n);
      us* t = c0; c0 = c1; c1 = t;
    }
  }

  transition_kernel<<<(n*64+255)/256,256,0,stream>>>(hA, hB, hBb0, n);

  // layer 2 (C=64)
  {
    us* c0 = hBb0; us* c1 = hBb1;
    mgemm_mfma<64><<<gblk,256,0,stream>>>(c0, Wtb2, mb, n);
    for (int i=0;i<3;i++){
      agg_kernel<64><<<((long long)n*8+255)/256,256,0,stream>>>(mb, rs2, esrc, aggb, n);
      if (i < 2)
        gru_mfma<64,true><<<gblk,256,0,stream>>>(aggb, c0, hB, Wihb2, Whhb2, bih2, bhh2,
                                                 Wtb2 + (i+1)*64*64, hB, c1, mb, n);
      else
        gru_mfma<64,false><<<gblk,256,0,stream>>>(aggb, c0, hB, Wihb2, Whhb2, bih2, bhh2,
                                                  nullptr, hB, c1, nullptr, n);
      us* t = c0; c0 = c1; c1 = t;
    }
  }

  head_mfma<<<gblk,256,0,stream>>>(hB, fc1wb, fc1b, fc2wpb, fc2bp, outp, n);
}

// Round 16
// 649.388 us; speedup vs baseline: 1.2899x; 1.2899x over previous
//
#include <hip/hip_runtime.h>
#include <math.h>

#define N_NODES 100000
#define N_EDGES 1600000
#define SCAN_BS 1024
#define NBK 8              // src buckets (src>>14): 16384 nodes = 2MB of m @C=64
#define BKSH 14
#define NBINS (N_NODES*NBK)

typedef __attribute__((ext_vector_type(8))) short bf8_t;   // 8 bf16 in 4 VGPRs
typedef __attribute__((ext_vector_type(4))) float f4_t;
typedef unsigned short us;
typedef unsigned long long ull;

__device__ __forceinline__ float sigmoidf_(float x){ return 1.f/(1.f + expf(-x)); }
__device__ __forceinline__ float eluf_(float x){ return x > 0.f ? x : expm1f(x); }
__device__ __forceinline__ us f2bf(float x){
  unsigned u = __float_as_uint(x);
  unsigned r = u + 0x7FFFu + ((u>>16)&1u);
  return (us)(r>>16);
}
__device__ __forceinline__ float bf2f(us v){
  return __uint_as_float(((unsigned)v)<<16);
}

// ---------------- fused weight prep (one kernel, segment-dispatched) ----------
__global__ void prep_all(const float* __restrict__ Wih1, const float* __restrict__ Whh1,
                         const float* __restrict__ Wih2, const float* __restrict__ Whh2,
                         const float* __restrict__ W1,   const float* __restrict__ W2,
                         const float* __restrict__ fc1w, const float* __restrict__ fc2w,
                         const float* __restrict__ fc2b,
                         us* Wihb1, us* Whhb1, us* Wihb2, us* Whhb2,
                         us* Wtb1, us* Wtb2, us* fc1wb, us* fc2wpb, float* fc2bp){
  int i = blockIdx.x*256 + threadIdx.x;
  if (i < 3072) { Wihb1[i]=f2bf(Wih1[i]); return; } i -= 3072;
  if (i < 3072) { Whhb1[i]=f2bf(Whh1[i]); return; } i -= 3072;
  if (i < 12288){ Wihb2[i]=f2bf(Wih2[i]); return; } i -= 12288;
  if (i < 12288){ Whhb2[i]=f2bf(Whh2[i]); return; } i -= 12288;
  if (i < 3072) { int k=i%32, c=(i/32)%32, m=i/1024;           // Wt[m][c][k] = W[m][k][c]
                  Wtb1[i]=f2bf(W1[m*1024 + k*32 + c]); return; } i -= 3072;
  if (i < 12288){ int k=i%64, c=(i/64)%64, m=i/4096;
                  Wtb2[i]=f2bf(W2[m*4096 + k*64 + c]); return; } i -= 12288;
  if (i < 8192) { fc1wb[i]=f2bf(fc1w[i]); return; } i -= 8192;
  if (i < 2048) { int c=i/128, k=i%128;
                  fc2wpb[i]=(c<10)?f2bf(fc2w[c*128+k]):(us)0; return; } i -= 2048;
  if (i < 16)   { fc2bp[i] = (i<10)? fc2b[i] : 0.f; }
}

// ---------------- bucketed CSR build: key = dst*NBK + (src>>BKSH) ----------
// (R15 lesson: two-pass partition scatter regressed — append tails bounce
//  cross-XCD. Single-pass random 8B scatter ~88us is the practical floor.)
__global__ void zero_counts(int* cnt, int* cur, int n){
  int i = blockIdx.x*blockDim.x + threadIdx.x;
  if (i < n){ cnt[i]=0; cur[i]=0; }
}
__global__ void count_kernel(const int* __restrict__ ei, int* __restrict__ cnt, int e){
  int i = blockIdx.x*blockDim.x + threadIdx.x;
  if (i < e){
    int s = ei[i], d = ei[N_EDGES + i];
    atomicAdd(&cnt[d*NBK + (s>>BKSH)], 1);
  }
}
__global__ void scan1_kernel(const int* __restrict__ cnt, int* __restrict__ pre,
                             int* __restrict__ bsum, int n){
  __shared__ int sh[SCAN_BS];
  int t = threadIdx.x, gi = blockIdx.x*SCAN_BS + t;
  int v = (gi < n) ? cnt[gi] : 0;
  sh[t] = v;
  __syncthreads();
  for (int off=1; off<SCAN_BS; off<<=1){
    int u = (t>=off)?sh[t-off]:0;
    __syncthreads();
    sh[t] += u;
    __syncthreads();
  }
  if (gi < n) pre[gi] = sh[t] - v;
  if (t == SCAN_BS-1) bsum[blockIdx.x] = sh[t];
}
__global__ void scan2_kernel(int* __restrict__ bsum, int nb){
  __shared__ int sh[1024];
  int t = threadIdx.x;
  int v = (t < nb) ? bsum[t] : 0;
  sh[t] = v;
  __syncthreads();
  for (int off=1; off<1024; off<<=1){
    int u = (t>=off)?sh[t-off]:0;
    __syncthreads();
    sh[t] += u;
    __syncthreads();
  }
  if (t < nb) bsum[t] = sh[t] - v;
}
__global__ void scan3_kernel(const int* __restrict__ pre, const int* __restrict__ bsum,
                             int* __restrict__ rs2, int total){
  int i = blockIdx.x*blockDim.x + threadIdx.x;
  if (i < total) rs2[i] = pre[i] + bsum[i/SCAN_BS];
  if (i == 0) rs2[total] = N_EDGES;
}
// 2 edges/thread, nontemporal packed store; bucket-grouped destinations
__global__ void scatter_kernel(const int* __restrict__ ei, const float* __restrict__ ea,
    const int* __restrict__ rs2, int* __restrict__ cur,
    long long* __restrict__ esrc, int e){
  int i0 = (blockIdx.x*blockDim.x + threadIdx.x)*2;
  #pragma unroll
  for (int j=0;j<2;j++){
    int i = i0 + j;
    if (i < e){
      int s = ei[i], d = ei[N_EDGES + i];
      int bin = d*NBK + (s>>BKSH);
      int p = rs2[bin] + atomicAdd(&cur[bin], 1);
      long long v = (long long)(unsigned)s
                  | ((long long)(unsigned)__float_as_int(ea[i]) << 32);
      __builtin_nontemporal_store(v, &esrc[p]);
    }
  }
}

// ---------------- elementwise (bf16-only state) ----------------
__global__ void pad_x_kernel(const float* __restrict__ x, us* __restrict__ hb, int n){
  int i = blockIdx.x*blockDim.x + threadIdx.x;
  if (i < n*32){
    int node = i >> 5, c = i & 31;
    hb[i] = (c < 16) ? f2bf(x[node*16 + c]) : (us)0;
  }
}
__global__ void transition_kernel(const us* __restrict__ h1b, us* __restrict__ h2b, int n){
  int i = blockIdx.x*blockDim.x + threadIdx.x;
  if (i < n*64){
    int node = i >> 6, c = i & 63;
    h2b[i] = (c < 32) ? f2bf(eluf_(bf2f(h1b[node*32 + c]))) : (us)0;
  }
}

// ---------------- m = h @ W via MFMA (layer-start only) ----------------
template<int C>
__global__ __launch_bounds__(256) void mgemm_mfma(const us* __restrict__ hb,
    const us* __restrict__ Wtb, us* __restrict__ mb, int n){
  constexpr int NT = C/16, KS = C/32;
  int l = threadIdx.x & 63, w = threadIdx.x >> 6;
  int mbase = blockIdx.x*64 + w*16;
  if (mbase >= n) return;
  int lr = l & 15, lk = (l >> 4)*8;
  f4_t acc[NT];
  #pragma unroll
  for (int t=0;t<NT;t++) acc[t] = f4_t{0.f,0.f,0.f,0.f};
  #pragma unroll
  for (int ks=0; ks<KS; ks++){
    int k0 = ks*32 + lk;
    bf8_t a = *(const bf8_t*)(hb + (size_t)(mbase+lr)*C + k0);
    #pragma unroll
    for (int t=0;t<NT;t++){
      bf8_t b = *(const bf8_t*)(Wtb + (size_t)(t*16+lr)*C + k0);
      acc[t] = __builtin_amdgcn_mfma_f32_16x16x32_bf16(a, b, acc[t], 0, 0, 0);
    }
  }
  int dr = (l>>4)*4;
  #pragma unroll
  for (int t=0;t<NT;t++){
    #pragma unroll
    for (int r=0;r<4;r++){
      int node = mbase + dr + r;
      if (node < n)
        mb[(size_t)node*C + t*16 + lr] = f2bf(acc[t][r]);
    }
  }
}

// ---------------- agg: 8 channels/lane via uint4 gathers, 4-deep pipeline ----
template<int C>
__global__ void agg_kernel(const us* __restrict__ mb, const int* __restrict__ rs2,
    const long long* __restrict__ esrc, us* __restrict__ aggb, int n_nodes){
  constexpr int GPN = C/8;
  int gid = blockIdx.x*blockDim.x + threadIdx.x;
  int nn = gid / GPN, g8 = gid % GPN;
  if (nn >= n_nodes) return;
  int s = rs2[nn*NBK], e = rs2[nn*NBK + NBK];
  float acc[8];
  #pragma unroll
  for (int j=0;j<8;j++) acc[j] = -__builtin_inff();
  const us* mbg = mb + g8*8;
  int i = s;
  for (; i+4<=e; i+=4){
    long long e0 = esrc[i], e1 = esrc[i+1], e2 = esrc[i+2], e3 = esrc[i+3];
    uint4 v0 = *(const uint4*)(mbg + (size_t)(unsigned)(e0 & 0xFFFFFFFF)*C);
    uint4 v1 = *(const uint4*)(mbg + (size_t)(unsigned)(e1 & 0xFFFFFFFF)*C);
    uint4 v2 = *(const uint4*)(mbg + (size_t)(unsigned)(e2 & 0xFFFFFFFF)*C);
    uint4 v3 = *(const uint4*)(mbg + (size_t)(unsigned)(e3 & 0xFFFFFFFF)*C);
    float w0 = __int_as_float((int)(e0>>32)), w1 = __int_as_float((int)(e1>>32));
    float w2 = __int_as_float((int)(e2>>32)), w3 = __int_as_float((int)(e3>>32));
    unsigned a0[4] = {v0.x, v0.y, v0.z, v0.w};
    unsigned a1[4] = {v1.x, v1.y, v1.z, v1.w};
    unsigned a2[4] = {v2.x, v2.y, v2.z, v2.w};
    unsigned a3[4] = {v3.x, v3.y, v3.z, v3.w};
    #pragma unroll
    for (int q=0;q<4;q++){
      float x0 = fmaxf(__uint_as_float(a0[q]<<16)*w0, __uint_as_float(a1[q]<<16)*w1);
      float x1 = fmaxf(__uint_as_float(a2[q]<<16)*w2, __uint_as_float(a3[q]<<16)*w3);
      float y0 = fmaxf(__uint_as_float(a0[q]&0xFFFF0000u)*w0, __uint_as_float(a1[q]&0xFFFF0000u)*w1);
      float y1 = fmaxf(__uint_as_float(a2[q]&0xFFFF0000u)*w2, __uint_as_float(a3[q]&0xFFFF0000u)*w3);
      acc[2*q]   = fmaxf(acc[2*q],   fmaxf(x0, x1));
      acc[2*q+1] = fmaxf(acc[2*q+1], fmaxf(y0, y1));
    }
  }
  for (; i<e; i++){
    long long e0 = esrc[i];
    uint4 v0 = *(const uint4*)(mbg + (size_t)(unsigned)(e0 & 0xFFFFFFFF)*C);
    float w0 = __int_as_float((int)(e0>>32));
    unsigned a0[4] = {v0.x, v0.y, v0.z, v0.w};
    #pragma unroll
    for (int q=0;q<4;q++){
      acc[2*q]   = fmaxf(acc[2*q],   __uint_as_float(a0[q]<<16)*w0);
      acc[2*q+1] = fmaxf(acc[2*q+1], __uint_as_float(a0[q]&0xFFFF0000u)*w0);
    }
  }
  unsigned r[8];
  #pragma unroll
  for (int j=0;j<8;j++) r[j] = (e > s) ? (unsigned)f2bf(acc[j]) : 0u;
  uint4 o;
  o.x = r[0] | (r[1]<<16); o.y = r[2] | (r[3]<<16);
  o.z = r[4] | (r[5]<<16); o.w = r[6] | (r[7]<<16);
  *(uint4*)(aggb + (size_t)nn*C + g8*8) = o;
}

// ---------------- fused GRU via MFMA; bf16 h state only -------------------
// gate's z*h term uses bf16 h (1 extra ULP/iter; 3x absmax headroom).
template<int C, bool COMPUTE_M>
__global__ __launch_bounds__(256) void gru_mfma(
    const us* __restrict__ aggb, const us* __restrict__ hbin,
    const us* __restrict__ Wihb, const us* __restrict__ Whhb,
    const float* __restrict__ bih, const float* __restrict__ bhh,
    const us* __restrict__ Wtb_next,
    us* __restrict__ hbout, us* __restrict__ mbout, int n){
  constexpr int NT = 3*C/16;
  constexpr int KS = C/32;
  constexpr int CT = C/16;
  constexpr int TST = C + 8;                     // LDS tile stride (bf16)
  constexpr int TSZ = COMPUTE_M ? 16*TST : 1;
  __shared__ us tlds[4][TSZ];
  int l = threadIdx.x & 63, w = threadIdx.x >> 6;
  int mbase = blockIdx.x*64 + w*16;
  int lr = l & 15, lk = (l >> 4)*8;
  f4_t accI[NT], accH[NT];
  #pragma unroll
  for (int t=0;t<NT;t++){ accI[t]=f4_t{0.f,0.f,0.f,0.f}; accH[t]=f4_t{0.f,0.f,0.f,0.f}; }
  #pragma unroll
  for (int ks=0; ks<KS; ks++){
    int k0 = ks*32 + lk;
    bf8_t aI = *(const bf8_t*)(aggb + (size_t)(mbase+lr)*C + k0);
    bf8_t aH = *(const bf8_t*)(hbin + (size_t)(mbase+lr)*C + k0);
    #pragma unroll
    for (int t=0;t<NT;t++){
      bf8_t bI = *(const bf8_t*)(Wihb + (size_t)(t*16+lr)*C + k0);
      accI[t] = __builtin_amdgcn_mfma_f32_16x16x32_bf16(aI, bI, accI[t], 0, 0, 0);
      bf8_t bH = *(const bf8_t*)(Whhb + (size_t)(t*16+lr)*C + k0);
      accH[t] = __builtin_amdgcn_mfma_f32_16x16x32_bf16(aH, bH, accH[t], 0, 0, 0);
    }
  }
  int dr = (l>>4)*4;
  us* tile = tlds[w];
  #pragma unroll
  for (int ct=0; ct<CT; ct++){
    int c = ct*16 + lr;
    float bR = bih[c],     cR = bhh[c];
    float bZ = bih[c+C],   cZ = bhh[c+C];
    float bN = bih[c+2*C], cN = bhh[c+2*C];
    #pragma unroll
    for (int r=0;r<4;r++){
      int i = mbase + dr + r;
      float giR = accI[ct][r] + bR,      ghR = accH[ct][r] + cR;
      float giZ = accI[CT+ct][r] + bZ,   ghZ = accH[CT+ct][r] + cZ;
      float giN = accI[2*CT+ct][r] + bN, ghN = accH[2*CT+ct][r] + cN;
      float rr = sigmoidf_(giR + ghR);
      float z  = sigmoidf_(giZ + ghZ);
      float nn = tanhf(giN + rr*ghN);
      float h  = bf2f(hbin[(size_t)i*C + c]);  // tail rows read adjacent ws: safe
      float ho = (1.f - z)*nn + z*h;
      us hob = f2bf(ho);
      if constexpr (COMPUTE_M)
        tile[(dr+r)*TST + c] = hob;
      if (i < n)
        hbout[(size_t)i*C + c] = hob;
    }
  }
  if constexpr (COMPUTE_M){
    __syncthreads();
    f4_t macc[CT];
    #pragma unroll
    for (int t=0;t<CT;t++) macc[t] = f4_t{0.f,0.f,0.f,0.f};
    #pragma unroll
    for (int ks=0; ks<KS; ks++){
      int k0 = ks*32 + lk;
      bf8_t a = *(const bf8_t*)(tile + lr*TST + k0);
      #pragma unroll
      for (int t=0;t<CT;t++){
        bf8_t b = *(const bf8_t*)(Wtb_next + (size_t)(t*16+lr)*C + k0);
        macc[t] = __builtin_amdgcn_mfma_f32_16x16x32_bf16(a, b, macc[t], 0, 0, 0);
      }
    }
    #pragma unroll
    for (int t=0;t<CT;t++){
      #pragma unroll
      for (int r=0;r<4;r++){
        int node = mbase + dr + r;
        if (node < n)
          mbout[(size_t)node*C + t*16 + lr] = f2bf(macc[t][r]);
      }
    }
  }
}

// ---------------- head via MFMA: elu -> fc1 -> elu -> fc2 -> log_softmax ----
__global__ __launch_bounds__(256) void head_mfma(const us* __restrict__ h2b,
    const us* __restrict__ fc1wb, const float* __restrict__ fc1b,
    const us* __restrict__ fc2wpb, const float* __restrict__ fc2bp,
    float* __restrict__ out, int n){
  __shared__ __align__(16) us lds[4][16*136];
  int l = threadIdx.x & 63, w = threadIdx.x >> 6;
  int mbase = blockIdx.x*64 + w*16;          // no early return: barrier stays uniform
  int lr = l & 15, lk = (l >> 4)*8;
  int dr = (l>>4)*4;
  // ---- fc1 ----
  f4_t acc1[8];
  #pragma unroll
  for (int t=0;t<8;t++) acc1[t] = f4_t{0.f,0.f,0.f,0.f};
  #pragma unroll
  for (int ks=0; ks<2; ks++){
    int k0 = ks*32 + lk;
    bf8_t hv = *(const bf8_t*)(h2b + (size_t)(mbase+lr)*64 + k0);  // tail: scratch, safe
    bf8_t a;
    #pragma unroll
    for (int j=0;j<8;j++)
      a[j] = (short)f2bf(eluf_(bf2f((us)hv[j])));
    #pragma unroll
    for (int t=0;t<8;t++){
      bf8_t b = *(const bf8_t*)(fc1wb + (size_t)(t*16+lr)*64 + k0);
      acc1[t] = __builtin_amdgcn_mfma_f32_16x16x32_bf16(a, b, acc1[t], 0, 0, 0);
    }
  }
  // ---- bias + elu, transpose through LDS ----
  us* tile = lds[w];
  #pragma unroll
  for (int t=0;t<8;t++){
    float b1 = fc1b[t*16 + lr];
    #pragma unroll
    for (int r=0;r<4;r++)
      tile[(dr+r)*136 + t*16 + lr] = f2bf(eluf_(acc1[t][r] + b1));
  }
  __syncthreads();
  // ---- fc2 ----
  f4_t acc2 = f4_t{0.f,0.f,0.f,0.f};
  #pragma unroll
  for (int ks=0; ks<4; ks++){
    int k0 = ks*32 + lk;
    bf8_t a = *(const bf8_t*)(tile + lr*136 + k0);
    bf8_t b = *(const bf8_t*)(fc2wpb + (size_t)lr*128 + k0);
    acc2 = __builtin_amdgcn_mfma_f32_16x16x32_bf16(a, b, acc2, 0, 0, 0);
  }
  // ---- log_softmax over classes (16 lanes = 16 cols, 10 valid) ----
  float b2 = fc2bp[lr];
  #pragma unroll
  for (int r=0;r<4;r++){
    float val = acc2[r] + b2;
    float vm = (lr < 10) ? val : -__builtin_inff();
    #pragma unroll
    for (int m=1;m<16;m<<=1) vm = fmaxf(vm, __shfl_xor(vm, m, 64));
    float ex = (lr < 10) ? expf(val - vm) : 0.f;
    #pragma unroll
    for (int m=1;m<16;m<<=1) ex += __shfl_xor(ex, m, 64);
    float lse = vm + logf(ex);
    int node = mbase + dr + r;
    if (lr < 10 && node < n) out[(size_t)node*10 + lr] = val - lse;
  }
}

extern "C" void kernel_launch(void* const* d_in, const int* in_sizes, int n_in,
                              void* d_out, int out_size, void* d_ws, size_t ws_size,
                              hipStream_t stream){
  const float* x    = (const float*)d_in[0];
  const int*   ei   = (const int*)  d_in[1];
  const float* ea   = (const float*)d_in[2];
  const float* W1   = (const float*)d_in[3];
  const float* Wih1 = (const float*)d_in[4];
  const float* Whh1 = (const float*)d_in[5];
  const float* bih1 = (const float*)d_in[6];
  const float* bhh1 = (const float*)d_in[7];
  const float* W2   = (const float*)d_in[8];
  const float* Wih2 = (const float*)d_in[9];
  const float* Whh2 = (const float*)d_in[10];
  const float* bih2 = (const float*)d_in[11];
  const float* bhh2 = (const float*)d_in[12];
  const float* fc1w = (const float*)d_in[13];
  const float* fc1b = (const float*)d_in[14];
  const float* fc2w = (const float*)d_in[15];
  const float* fc2b = (const float*)d_in[16];
  float* outp = (float*)d_out;

  char* ws = (char*)d_ws;
  size_t off = 0;
  auto alloc = [&](size_t bytes)->void*{
    void* p = ws + off;
    off += (bytes + 255) & ~size_t(255);
    return p;
  };
  us* hAb0    = (us*)alloc(sizeof(us)*N_NODES*32);
  us* hAb1    = (us*)alloc(sizeof(us)*N_NODES*32);
  us* hBb0    = (us*)alloc(sizeof(us)*N_NODES*64);
  us* hBb1    = (us*)alloc(sizeof(us)*N_NODES*64);
  us* mb      = (us*)alloc(sizeof(us)*N_NODES*64);
  us* aggb    = (us*)alloc(sizeof(us)*N_NODES*64);
  int* rs2    = (int*)alloc(sizeof(int)*(NBINS+1));
  int* cnt    = (int*)alloc(sizeof(int)*NBINS);
  int* cur    = (int*)alloc(sizeof(int)*NBINS);
  int* pre    = (int*)alloc(sizeof(int)*NBINS);
  int* bsum   = (int*)alloc(sizeof(int)*1024);
  long long* esrc = (long long*)alloc(sizeof(long long)*N_EDGES);
  us* Wihb1   = (us*)alloc(sizeof(us)*96*32);
  us* Whhb1   = (us*)alloc(sizeof(us)*96*32);
  us* Wihb2   = (us*)alloc(sizeof(us)*192*64);
  us* Whhb2   = (us*)alloc(sizeof(us)*192*64);
  us* Wtb1    = (us*)alloc(sizeof(us)*3*32*32);
  us* Wtb2    = (us*)alloc(sizeof(us)*3*64*64);
  us* fc1wb   = (us*)alloc(sizeof(us)*128*64);
  us* fc2wpb  = (us*)alloc(sizeof(us)*16*128);
  float* fc2bp= (float*)alloc(sizeof(float)*16);
  (void)ws_size; (void)in_sizes; (void)n_in; (void)out_size;

  const int n = N_NODES, e = N_EDGES;
  const int nbk = (NBINS + SCAN_BS - 1)/SCAN_BS;    // 782 <= 1024 (scan2 limit)
  const int gblk = (n + 63)/64;                      // 1563

  // fused weight prep: 56336 elements
  prep_all<<<(56336+255)/256,256,0,stream>>>(Wih1, Whh1, Wih2, Whh2, W1, W2,
      fc1w, fc2w, fc2b, Wihb1, Whhb1, Wihb2, Whhb2, Wtb1, Wtb2, fc1wb, fc2wpb, fc2bp);

  // bucketed CSR build (single-pass scatter)
  zero_counts<<<(NBINS+255)/256,256,0,stream>>>(cnt, cur, NBINS);
  count_kernel<<<(e+255)/256,256,0,stream>>>(ei, cnt, e);
  scan1_kernel<<<nbk,SCAN_BS,0,stream>>>(cnt, pre, bsum, NBINS);
  scan2_kernel<<<1,1024,0,stream>>>(bsum, nbk);
  scan3_kernel<<<(NBINS+255)/256,256,0,stream>>>(pre, bsum, rs2, NBINS);
  scatter_kernel<<<(e/2+255)/256,256,0,stream>>>(ei, ea, rs2, cur, esrc, e);

  // layer 1 (C=32)
  pad_x_kernel<<<(n*32+255)/256,256,0,stream>>>(x, hAb0, n);
  us* l1fin;
  {
    us* c0 = hAb0; us* c1 = hAb1;
    mgemm_mfma<32><<<gblk,256,0,stream>>>(c0, Wtb1, mb, n);
    for (int i=0;i<3;i++){
      agg_kernel<32><<<((long long)n*4+255)/256,256,0,stream>>>(mb, rs2, esrc, aggb, n);
      if (i < 2)
        gru_mfma<32,true><<<gblk,256,0,stream>>>(aggb, c0, Wihb1, Whhb1, bih1, bhh1,
                                                 Wtb1 + (i+1)*32*32, c1, mb, n);
      else
        gru_mfma<32,false><<<gblk,256,0,stream>>>(aggb, c0, Wihb1, Whhb1, bih1, bhh1,
                                                  nullptr, c1, nullptr, n);
      us* t = c0; c0 = c1; c1 = t;
    }
    l1fin = c0;
  }

  transition_kernel<<<(n*64+255)/256,256,0,stream>>>(l1fin, hBb0, n);

  // layer 2 (C=64)
  us* l2fin;
  {
    us* c0 = hBb0; us* c1 = hBb1;
    mgemm_mfma<64><<<gblk,256,0,stream>>>(c0, Wtb2, mb, n);
    for (int i=0;i<3;i++){
      agg_kernel<64><<<((long long)n*8+255)/256,256,0,stream>>>(mb, rs2, esrc, aggb, n);
      if (i < 2)
        gru_mfma<64,true><<<gblk,256,0,stream>>>(aggb, c0, Wihb2, Whhb2, bih2, bhh2,
                                                 Wtb2 + (i+1)*64*64, c1, mb, n);
      else
        gru_mfma<64,false><<<gblk,256,0,stream>>>(aggb, c0, Wihb2, Whhb2, bih2, bhh2,
                                                  nullptr, c1, nullptr, n);
      us* t = c0; c0 = c1; c1 = t;
    }
    l2fin = c0;
  }

  head_mfma<<<gblk,256,0,stream>>>(l2fin, fc1wb, fc1b, fc2wpb, fc2bp, outp, n);
}